// Round 16
// baseline (90.293 us; speedup 1.0000x reference)
//
#include <hip/hip_runtime.h>

typedef short short8 __attribute__((ext_vector_type(8)));
typedef float f32x4 __attribute__((ext_vector_type(4)));
typedef unsigned long long u64;

#define NE 1024
#define D 64
#define HW 4096
#define NTOK 65536
#define MARGIN 3.0e-3f     // global-threshold margin (proven R3/R5/R12/R13/R15)
#define FLT_MAX_F 3.402823466e+38f

// ws: bn f32[1024]@0 ; ebf u16[65536]@4096   (132 KB, well under proven 256 MiB)
#define WS_BN  0
#define WS_EBF 4096

__device__ __forceinline__ unsigned short f2bf(float f) {   // RNE f32->bf16
    unsigned u = __float_as_uint(f);
    return (unsigned short)((u + 0x7fffu + ((u >> 16) & 1u)) >> 16);
}

// numpy pairwise sum of squares, n=64 (frozen — exact since R2)
__device__ __forceinline__ float np_sum64_sq(const float* v) {
    float s[8];
#pragma unroll
    for (int j = 0; j < 8; ++j) s[j] = __fmul_rn(v[j], v[j]);
#pragma unroll
    for (int i = 8; i < 64; i += 8) {
#pragma unroll
        for (int j = 0; j < 8; ++j)
            s[j] = __fadd_rn(s[j], __fmul_rn(v[i + j], v[i + j]));
    }
    return __fadd_rn(__fadd_rn(__fadd_rn(s[0], s[1]), __fadd_rn(s[2], s[3])),
                     __fadd_rn(__fadd_rn(s[4], s[5]), __fadd_rn(s[6], s[7])));
}

__global__ __launch_bounds__(256) void kP_prep(
        const float* __restrict__ cb, float* __restrict__ bn,
        unsigned short* __restrict__ ebf) {
    const int gid = blockIdx.x * 256 + threadIdx.x;   // 65536 threads
    ebf[gid] = f2bf(cb[gid]);
    if (gid < NE) {
        float row[D];
        const float4* r4 = reinterpret_cast<const float4*>(cb + (size_t)gid * D);
#pragma unroll
        for (int i = 0; i < 16; ++i) {
            float4 v = r4[i];
            row[4*i+0] = v.x; row[4*i+1] = v.y; row[4*i+2] = v.z; row[4*i+3] = v.w;
        }
        bn[gid] = np_sum64_sq(row);
    }
}

// one block = 128 tokens x all 1024 codes: min + mark (LDS mask) + exact
// rerank + gather, fused. All numerics byte-identical to the R15 pipeline.
__global__ __launch_bounds__(256, 2) void k_mega(
        const float* __restrict__ in, const unsigned short* __restrict__ ebf,
        const float* __restrict__ bn_g, const float* __restrict__ cb,
        float* __restrict__ out) {
    __shared__ unsigned short ebq[128 * 64];    // 16 KB staging tile (swizzled)
    __shared__ float sbn[NE];                   // 4 KB
    __shared__ u64 lmask[128 * 16];             // 16 KB per-token candidate bits
    __shared__ unsigned short win_s[128];

    const int tid  = threadIdx.x;
    const int lane = tid & 63, w = tid >> 6;
    const int lcol = lane & 15, lhi = lane >> 4, lrow = lhi * 4;
    const int tokw = blockIdx.x * 128 + w * 32;
    const int b = tokw >> 12, hwb = tokw & 4095;

    {   // zero LDS mask
        int4* mz = (int4*)lmask;
#pragma unroll
        for (int i = 0; i < 4; ++i) mz[tid + i * 256] = int4{0, 0, 0, 0};
    }
#pragma unroll
    for (int i = 0; i < 4; ++i) sbn[tid + i * 256] = bn_g[tid + i * 256];

    // B fragments from input (frozen build, proven R4-R15)
    const float* xbase = in + (size_t)b * (D * HW);
    const int hw0 = hwb + lcol, hw1 = hw0 + 16;
    const int kb = lhi * 8;
    short8 B00, B01, B10, B11;
    {
        const float* p;
        p = xbase + (size_t)kb * HW + hw0;
#pragma unroll
        for (int j = 0; j < 8; ++j) B00[j] = (short)f2bf(p[(size_t)j * HW]);
        p = xbase + (size_t)(kb + 32) * HW + hw0;
#pragma unroll
        for (int j = 0; j < 8; ++j) B01[j] = (short)f2bf(p[(size_t)j * HW]);
        p = xbase + (size_t)kb * HW + hw1;
#pragma unroll
        for (int j = 0; j < 8; ++j) B10[j] = (short)f2bf(p[(size_t)j * HW]);
        p = xbase + (size_t)(kb + 32) * HW + hw1;
#pragma unroll
        for (int j = 0; j < 8; ++j) B11[j] = (short)f2bf(p[(size_t)j * HW]);
    }

    const int swz   = (lcol & 7) << 4;
    const int aoff0 = lcol * 128 + ((lhi * 16) ^ swz);
    const int aoff1 = lcol * 128 + ((64 + lhi * 16) ^ swz);

#define STAGE_CHUNK(C)                                                        \
    {                                                                         \
        const char* src = (const char*)(ebf + (size_t)(C) * 128 * 64);        \
        _Pragma("unroll")                                                     \
        for (int i = 0; i < 4; ++i) {                                         \
            int L = (tid + i * 256) * 16;                                     \
            int row = L >> 7, wi = L & 127;                                   \
            int4 v = *(const int4*)(src + L);                                 \
            *(int4*)((char*)ebq + row * 128 + (wi ^ ((row & 7) << 4))) = v;   \
        }                                                                     \
    }

#define CHUNK_MFMA(C, CT)                                                     \
    const char* lp = (const char*)ebq + (CT) * 2048;                          \
    short8 A0 = *(const short8*)(lp + aoff0);                                 \
    short8 A1 = *(const short8*)(lp + aoff1);                                 \
    f32x4 bnv = *(const f32x4*)(sbn + (C) * 128 + (CT) * 16 + lrow);          \
    f32x4 acc = {0.f, 0.f, 0.f, 0.f};                                         \
    acc = __builtin_amdgcn_mfma_f32_16x16x32_bf16(A0, B00, acc, 0, 0, 0);     \
    acc = __builtin_amdgcn_mfma_f32_16x16x32_bf16(A1, B01, acc, 0, 0, 0);     \
    f32x4 ac2 = {0.f, 0.f, 0.f, 0.f};                                         \
    ac2 = __builtin_amdgcn_mfma_f32_16x16x32_bf16(A0, B10, ac2, 0, 0, 0);     \
    ac2 = __builtin_amdgcn_mfma_f32_16x16x32_bf16(A1, B11, ac2, 0, 0, 0);

    // ---- pass A: per-token min over ALL chunks (block sees whole codebook;
    //      fminf is associative -> value identical to atomicMin version) ----
    float v10 = FLT_MAX_F, v11 = FLT_MAX_F;
    for (int c = 0; c < 8; ++c) {
        __syncthreads();
        STAGE_CHUNK(c)
        __syncthreads();
#pragma unroll
        for (int ct = 0; ct < 8; ++ct) {
            CHUNK_MFMA(c, ct)
#pragma unroll
            for (int r = 0; r < 4; ++r) {
                v10 = fminf(v10, __fmaf_rn(-2.0f, acc[r], bnv[r]));
                v11 = fminf(v11, __fmaf_rn(-2.0f, ac2[r], bnv[r]));
            }
        }
    }
    v10 = fminf(v10, __shfl_xor(v10, 16)); v10 = fminf(v10, __shfl_xor(v10, 32));
    v11 = fminf(v11, __shfl_xor(v11, 16)); v11 = fminf(v11, __shfl_xor(v11, 32));
    const float thr0 = v10 + MARGIN, thr1 = v11 + MARGIN;
    const int tA = w * 32 + lcol, tB = tA + 16;       // token-local indices

    // ---- pass B: bit-identical recompute, mark into LDS bitmask ----
    for (int c = 0; c < 8; ++c) {
        __syncthreads();
        STAGE_CHUNK(c)
        __syncthreads();
#pragma unroll
        for (int ct = 0; ct < 8; ++ct) {
            CHUNK_MFMA(c, ct)
            const int kg = c * 128 + ct * 16 + lrow;
#pragma unroll
            for (int r = 0; r < 4; ++r) {
                float t0 = __fmaf_rn(-2.0f, acc[r], bnv[r]);
                if (t0 <= thr0)
                    atomicOr(&lmask[tA * 16 + ((kg + r) >> 6)], 1ull << ((kg + r) & 63));
                float t1 = __fmaf_rn(-2.0f, ac2[r], bnv[r]);
                if (t1 <= thr1)
                    atomicOr(&lmask[tB * 16 + ((kg + r) >> 6)], 1ull << ((kg + r) & 63));
            }
        }
    }
    __syncthreads();

    // ---- rerank: 2 threads/token, frozen-exact, order-independent key min ----
    {
        const int tok_l = tid >> 1, sub = tid & 1;
        const int tok = blockIdx.x * 128 + tok_l;
        const int tb = tok >> 12, thw = tok & 4095;
        const float* x = in + (size_t)tb * (D * HW) + thw;
        float xv[D];
#pragma unroll
        for (int d = 0; d < D; ++d) xv[d] = x[(size_t)d * HW];
        const float a = np_sum64_sq(xv);                      // frozen

        u64 best = ~0ull;
        int kp = -1;
        int pos = 0;
        for (int wd = 0; wd < 16; ++wd) {
            u64 m = lmask[tok_l * 16 + wd];
            while (m) {
                const int k = wd * 64 + (int)__builtin_ctzll(m);
                m &= m - 1;
                if (((pos++) & 1) != sub) continue;
                if (kp < 0) { kp = k; continue; }
                // pair: two independent frozen chains (each sequential asc d)
                const float* e0 = cb + (size_t)kp * D;
                const float* e1 = cb + (size_t)k * D;
                float d0 = 0.f, d1 = 0.f;
#pragma unroll
                for (int d = 0; d < 64; ++d) {
                    d0 = __fmaf_rn(xv[d], e0[d], d0);
                    d1 = __fmaf_rn(xv[d], e1[d], d1);
                }
                float q0 = __fsub_rn(__fadd_rn(a, bn_g[kp]), __fmul_rn(2.0f, d0));
                float q1 = __fsub_rn(__fadd_rn(a, bn_g[k]),  __fmul_rn(2.0f, d1));
                u64 key0 = (((u64)__float_as_uint(q0)) << 32) | (unsigned)kp;
                u64 key1 = (((u64)__float_as_uint(q1)) << 32) | (unsigned)k;
                u64 kmin = key0 < key1 ? key0 : key1;
                best = best < kmin ? best : kmin;
                kp = -1;
            }
        }
        if (kp >= 0) {
            const float* e0 = cb + (size_t)kp * D;
            float d0 = 0.f;
#pragma unroll
            for (int d = 0; d < 64; ++d) d0 = __fmaf_rn(xv[d], e0[d], d0);
            float q0 = __fsub_rn(__fadd_rn(a, bn_g[kp]), __fmul_rn(2.0f, d0));
            u64 key0 = (((u64)__float_as_uint(q0)) << 32) | (unsigned)kp;
            best = best < key0 ? best : key0;
        }
        {
            u64 v = __shfl_xor(best, 1);      // tid and tid^1 are same wave
            best = best < v ? best : v;
        }
        if (sub == 0) win_s[tok_l] = (unsigned short)(best & 0x3FFull);
    }
    __syncthreads();

    // ---- gather: 2 threads/token write the winning codebook row ----
    {
        const int tok_l = tid >> 1, half = tid & 1;
        const int tok = blockIdx.x * 128 + tok_l;
        const int gb = tok >> 12, ghw = tok & 4095;
        const unsigned k = win_s[tok_l];
        const float4* er = reinterpret_cast<const float4*>(cb + (size_t)k * D + half * 32);
        float* ot = out + (size_t)gb * (D * HW) + ghw;
#pragma unroll
        for (int i = 0; i < 8; ++i) {
            float4 e = er[i];
            ot[(size_t)(half * 32 + 4*i + 0) * HW] = e.x;
            ot[(size_t)(half * 32 + 4*i + 1) * HW] = e.y;
            ot[(size_t)(half * 32 + 4*i + 2) * HW] = e.z;
            ot[(size_t)(half * 32 + 4*i + 3) * HW] = e.w;
        }
    }
}

extern "C" void kernel_launch(void* const* d_in, const int* in_sizes, int n_in,
                              void* d_out, int out_size, void* d_ws, size_t ws_size,
                              hipStream_t stream) {
    const float* in  = (const float*)d_in[0];
    const float* cb  = (const float*)d_in[1];
    float*       out = (float*)d_out;
    char*        ws  = (char*)d_ws;

    float*          bn  = (float*)(ws + WS_BN);
    unsigned short* ebf = (unsigned short*)(ws + WS_EBF);

    hipLaunchKernelGGL(kP_prep, dim3(256), dim3(256), 0, stream, cb, bn, ebf);
    hipLaunchKernelGGL(k_mega,  dim3(512), dim3(256), 0, stream, in, ebf, bn, cb, out);
}

// Round 17
// 76.207 us; speedup vs baseline: 1.1848x; 1.1848x over previous
//
#include <hip/hip_runtime.h>

typedef short short8 __attribute__((ext_vector_type(8)));
typedef float f32x4 __attribute__((ext_vector_type(4)));
typedef unsigned long long u64;

#define NE 1024
#define D 64
#define HW 4096
#define MARGIN 3.0e-3f     // global-threshold margin (proven R3/R5/R12/R13/R15)
#define FLT_MAX_F 3.402823466e+38f
#define MSTRIDE 17         // lmask row stride in u64 (pad: kills bank conflicts)

// ws: bn f32[1024]@0 ; ebf u16[65536]@4096
#define WS_BN  0
#define WS_EBF 4096

__device__ __forceinline__ unsigned short f2bf(float f) {   // RNE f32->bf16
    unsigned u = __float_as_uint(f);
    return (unsigned short)((u + 0x7fffu + ((u >> 16) & 1u)) >> 16);
}

// numpy pairwise sum of squares, n=64 (frozen — exact since R2)
__device__ __forceinline__ float np_sum64_sq(const float* v) {
    float s[8];
#pragma unroll
    for (int j = 0; j < 8; ++j) s[j] = __fmul_rn(v[j], v[j]);
#pragma unroll
    for (int i = 8; i < 64; i += 8) {
#pragma unroll
        for (int j = 0; j < 8; ++j)
            s[j] = __fadd_rn(s[j], __fmul_rn(v[i + j], v[i + j]));
    }
    return __fadd_rn(__fadd_rn(__fadd_rn(s[0], s[1]), __fadd_rn(s[2], s[3])),
                     __fadd_rn(__fadd_rn(s[4], s[5]), __fadd_rn(s[6], s[7])));
}

__global__ __launch_bounds__(256) void kP_prep(
        const float* __restrict__ cb, float* __restrict__ bn,
        unsigned short* __restrict__ ebf) {
    const int gid = blockIdx.x * 256 + threadIdx.x;   // 65536 threads
    ebf[gid] = f2bf(cb[gid]);
    if (gid < NE) {
        float row[D];
        const float4* r4 = reinterpret_cast<const float4*>(cb + (size_t)gid * D);
#pragma unroll
        for (int i = 0; i < 16; ++i) {
            float4 v = r4[i];
            row[4*i+0] = v.x; row[4*i+1] = v.y; row[4*i+2] = v.z; row[4*i+3] = v.w;
        }
        bn[gid] = np_sum64_sq(row);
    }
}

// one block = 128 tokens x all 1024 codes; async-split staging, non-atomic
// LDS mask, in-register rerank. Numerics byte-identical to R15/R16 pipeline.
__global__ __launch_bounds__(256, 4) void k_mega(
        const float* __restrict__ in, const unsigned short* __restrict__ ebf,
        const float* __restrict__ bn_g, const float* __restrict__ cb,
        float* __restrict__ out) {
    __shared__ unsigned short ebq[128 * 64];    // 16 KB staging tile (swizzled)
    __shared__ float sbn[NE];                   // 4 KB
    __shared__ u64 lmask[128 * MSTRIDE];        // 17 KB, no init needed (overwritten)
    __shared__ unsigned short win_s[128];

    const int tid  = threadIdx.x;
    const int lane = tid & 63, w = tid >> 6;
    const int lcol = lane & 15, lhi = lane >> 4, lrow = lhi * 4;
    const int tokw = blockIdx.x * 128 + w * 32;
    const int b = tokw >> 12, hwb = tokw & 4095;

#pragma unroll
    for (int i = 0; i < 4; ++i) sbn[tid + i * 256] = bn_g[tid + i * 256];

    // B fragments from input (frozen build, proven R4-R16)
    const float* xbase = in + (size_t)b * (D * HW);
    const int hw0 = hwb + lcol, hw1 = hw0 + 16;
    const int kb = lhi * 8;
    short8 B00, B01, B10, B11;
    {
        const float* p;
        p = xbase + (size_t)kb * HW + hw0;
#pragma unroll
        for (int j = 0; j < 8; ++j) B00[j] = (short)f2bf(p[(size_t)j * HW]);
        p = xbase + (size_t)(kb + 32) * HW + hw0;
#pragma unroll
        for (int j = 0; j < 8; ++j) B01[j] = (short)f2bf(p[(size_t)j * HW]);
        p = xbase + (size_t)kb * HW + hw1;
#pragma unroll
        for (int j = 0; j < 8; ++j) B10[j] = (short)f2bf(p[(size_t)j * HW]);
        p = xbase + (size_t)(kb + 32) * HW + hw1;
#pragma unroll
        for (int j = 0; j < 8; ++j) B11[j] = (short)f2bf(p[(size_t)j * HW]);
    }

    const int swz   = (lcol & 7) << 4;
    const int aoff0 = lcol * 128 + ((lhi * 16) ^ swz);
    const int aoff1 = lcol * 128 + ((64 + lhi * 16) ^ swz);

    int4 pf0, pf1, pf2, pf3;   // prefetch registers (async-split staging)
#define LOADC(C) { const int4* s_ = (const int4*)(ebf + (size_t)(C) * 8192);  \
                   pf0 = s_[tid]; pf1 = s_[tid + 256];                        \
                   pf2 = s_[tid + 512]; pf3 = s_[tid + 768]; }
#define WRITEC() { int4 t_[4] = {pf0, pf1, pf2, pf3};                         \
    _Pragma("unroll")                                                         \
    for (int i = 0; i < 4; ++i) {                                             \
        int L = (tid + i * 256) * 16;                                         \
        int row = L >> 7, wi = L & 127;                                       \
        *(int4*)((char*)ebq + row * 128 + (wi ^ ((row & 7) << 4))) = t_[i];   \
    } }

#define CHUNK_MFMA(C, CT)                                                     \
    const char* lp = (const char*)ebq + (CT) * 2048;                          \
    short8 A0 = *(const short8*)(lp + aoff0);                                 \
    short8 A1 = *(const short8*)(lp + aoff1);                                 \
    f32x4 bnv = *(const f32x4*)(sbn + (C) * 128 + (CT) * 16 + lrow);          \
    f32x4 acc = {0.f, 0.f, 0.f, 0.f};                                         \
    acc = __builtin_amdgcn_mfma_f32_16x16x32_bf16(A0, B00, acc, 0, 0, 0);     \
    acc = __builtin_amdgcn_mfma_f32_16x16x32_bf16(A1, B01, acc, 0, 0, 0);     \
    f32x4 ac2 = {0.f, 0.f, 0.f, 0.f};                                         \
    ac2 = __builtin_amdgcn_mfma_f32_16x16x32_bf16(A0, B10, ac2, 0, 0, 0);     \
    ac2 = __builtin_amdgcn_mfma_f32_16x16x32_bf16(A1, B11, ac2, 0, 0, 0);

    // ---- pass A: per-token min over all chunks (fminf associative) ----
    float v10 = FLT_MAX_F, v11 = FLT_MAX_F;
    LOADC(0)
    for (int c = 0; c < 8; ++c) {
        __syncthreads();
        WRITEC()
        __syncthreads();
        LOADC(c < 7 ? c + 1 : 0)        // c==7 prefetches chunk 0 for pass B
#pragma unroll
        for (int ct = 0; ct < 8; ++ct) {
            CHUNK_MFMA(c, ct)
#pragma unroll
            for (int r = 0; r < 4; ++r) {
                v10 = fminf(v10, __fmaf_rn(-2.0f, acc[r], bnv[r]));
                v11 = fminf(v11, __fmaf_rn(-2.0f, ac2[r], bnv[r]));
            }
        }
    }
    v10 = fminf(v10, __shfl_xor(v10, 16)); v10 = fminf(v10, __shfl_xor(v10, 32));
    v11 = fminf(v11, __shfl_xor(v11, 16)); v11 = fminf(v11, __shfl_xor(v11, 32));
    const float thr0 = v10 + MARGIN, thr1 = v11 + MARGIN;
    const int tA = w * 32 + lcol, tB = tA + 16;       // token-local indices

    // ---- pass B: bit-identical recompute; marks assembled in registers,
    //      OR-combined across the 4 lhi lanes, stored non-atomically ----
    for (int c = 0; c < 8; ++c) {
        __syncthreads();
        WRITEC()
        __syncthreads();
        if (c < 7) LOADC(c + 1)
        u64 w0a = 0, w1a = 0, w0b = 0, w1b = 0;
#pragma unroll
        for (int ct = 0; ct < 8; ++ct) {
            CHUNK_MFMA(c, ct)
#pragma unroll
            for (int r = 0; r < 4; ++r) {
                const int bit = (ct & 3) * 16 + lrow + r;   // j & 63
                float t0 = __fmaf_rn(-2.0f, acc[r], bnv[r]);
                if (t0 <= thr0) { if (ct < 4) w0a |= 1ull << bit; else w1a |= 1ull << bit; }
                float t1 = __fmaf_rn(-2.0f, ac2[r], bnv[r]);
                if (t1 <= thr1) { if (ct < 4) w0b |= 1ull << bit; else w1b |= 1ull << bit; }
            }
        }
        w0a |= __shfl_xor(w0a, 16); w0a |= __shfl_xor(w0a, 32);
        w1a |= __shfl_xor(w1a, 16); w1a |= __shfl_xor(w1a, 32);
        w0b |= __shfl_xor(w0b, 16); w0b |= __shfl_xor(w0b, 32);
        w1b |= __shfl_xor(w1b, 16); w1b |= __shfl_xor(w1b, 32);
        if (lhi == 0) {
            lmask[tA * MSTRIDE + 2 * c]     = w0a;
            lmask[tA * MSTRIDE + 2 * c + 1] = w1a;
            lmask[tB * MSTRIDE + 2 * c]     = w0b;
            lmask[tB * MSTRIDE + 2 * c + 1] = w1b;
        }
    }
    __syncthreads();

    // ---- rerank: 2 threads/token, frozen-exact, order-independent key min ----
    {
        const int tok_l = tid >> 1, sub = tid & 1;
        const int tok = blockIdx.x * 128 + tok_l;
        const int tb = tok >> 12, thw = tok & 4095;
        const float* x = in + (size_t)tb * (D * HW) + thw;
        float xv[D];
#pragma unroll
        for (int d = 0; d < D; ++d) xv[d] = x[(size_t)d * HW];
        const float a = np_sum64_sq(xv);                      // frozen

        u64 best = ~0ull;
        int kp = -1;
        int pos = 0;
        for (int wd = 0; wd < 16; ++wd) {
            u64 m = lmask[tok_l * MSTRIDE + wd];
            while (m) {
                const int k = wd * 64 + (int)__builtin_ctzll(m);
                m &= m - 1;
                if (((pos++) & 1) != sub) continue;
                if (kp < 0) { kp = k; continue; }
                const float* e0 = cb + (size_t)kp * D;
                const float* e1 = cb + (size_t)k * D;
                float d0 = 0.f, d1 = 0.f;
#pragma unroll
                for (int d = 0; d < 64; ++d) {
                    d0 = __fmaf_rn(xv[d], e0[d], d0);
                    d1 = __fmaf_rn(xv[d], e1[d], d1);
                }
                float q0 = __fsub_rn(__fadd_rn(a, bn_g[kp]), __fmul_rn(2.0f, d0));
                float q1 = __fsub_rn(__fadd_rn(a, bn_g[k]),  __fmul_rn(2.0f, d1));
                u64 key0 = (((u64)__float_as_uint(q0)) << 32) | (unsigned)kp;
                u64 key1 = (((u64)__float_as_uint(q1)) << 32) | (unsigned)k;
                u64 kmin = key0 < key1 ? key0 : key1;
                best = best < kmin ? best : kmin;
                kp = -1;
            }
        }
        if (kp >= 0) {
            const float* e0 = cb + (size_t)kp * D;
            float d0 = 0.f;
#pragma unroll
            for (int d = 0; d < 64; ++d) d0 = __fmaf_rn(xv[d], e0[d], d0);
            float q0 = __fsub_rn(__fadd_rn(a, bn_g[kp]), __fmul_rn(2.0f, d0));
            u64 key0 = (((u64)__float_as_uint(q0)) << 32) | (unsigned)kp;
            best = best < key0 ? best : key0;
        }
        {
            u64 v = __shfl_xor(best, 1);      // tid and tid^1 are same wave
            best = best < v ? best : v;
        }
        if (sub == 0) win_s[tok_l] = (unsigned short)(best & 0x3FFull);
    }
    __syncthreads();

    // ---- gather: 2 threads/token write the winning codebook row ----
    {
        const int tok_l = tid >> 1, half = tid & 1;
        const int tok = blockIdx.x * 128 + tok_l;
        const int gb = tok >> 12, ghw = tok & 4095;
        const unsigned k = win_s[tok_l];
        const float4* er = reinterpret_cast<const float4*>(cb + (size_t)k * D + half * 32);
        float* ot = out + (size_t)gb * (D * HW) + ghw;
#pragma unroll
        for (int i = 0; i < 8; ++i) {
            float4 e = er[i];
            ot[(size_t)(half * 32 + 4*i + 0) * HW] = e.x;
            ot[(size_t)(half * 32 + 4*i + 1) * HW] = e.y;
            ot[(size_t)(half * 32 + 4*i + 2) * HW] = e.z;
            ot[(size_t)(half * 32 + 4*i + 3) * HW] = e.w;
        }
    }
}

extern "C" void kernel_launch(void* const* d_in, const int* in_sizes, int n_in,
                              void* d_out, int out_size, void* d_ws, size_t ws_size,
                              hipStream_t stream) {
    const float* in  = (const float*)d_in[0];
    const float* cb  = (const float*)d_in[1];
    float*       out = (float*)d_out;
    char*        ws  = (char*)d_ws;

    float*          bn  = (float*)(ws + WS_BN);
    unsigned short* ebf = (unsigned short*)(ws + WS_EBF);

    hipLaunchKernelGGL(kP_prep, dim3(256), dim3(256), 0, stream, cb, bn, ebf);
    hipLaunchKernelGGL(k_mega,  dim3(512), dim3(256), 0, stream, in, ebf, bn, cb, out);
}

// Round 18
// 75.236 us; speedup vs baseline: 1.2001x; 1.0129x over previous
//
#include <hip/hip_runtime.h>

typedef short short8 __attribute__((ext_vector_type(8)));
typedef float f32x4 __attribute__((ext_vector_type(4)));
typedef unsigned long long u64;

#define NE 1024
#define D 64
#define HW 4096
#define MARGIN 3.0e-3f     // t-space margin (proven R3/R5/R12/R13/R15); acc-space = M/2
#define FLT_MAX_F 3.402823466e+38f
#define MSTRIDE 17         // lmask row stride in u64 (pad: kills bank conflicts)

// ws: bn f32[1024]@0 ; ebf u16[65536]@4096
#define WS_BN  0
#define WS_EBF 4096

__device__ __forceinline__ unsigned short f2bf(float f) {   // RNE f32->bf16
    unsigned u = __float_as_uint(f);
    return (unsigned short)((u + 0x7fffu + ((u >> 16) & 1u)) >> 16);
}

// numpy pairwise sum of squares, n=64 (frozen — exact since R2)
__device__ __forceinline__ float np_sum64_sq(const float* v) {
    float s[8];
#pragma unroll
    for (int j = 0; j < 8; ++j) s[j] = __fmul_rn(v[j], v[j]);
#pragma unroll
    for (int i = 8; i < 64; i += 8) {
#pragma unroll
        for (int j = 0; j < 8; ++j)
            s[j] = __fadd_rn(s[j], __fmul_rn(v[i + j], v[i + j]));
    }
    return __fadd_rn(__fadd_rn(__fadd_rn(s[0], s[1]), __fadd_rn(s[2], s[3])),
                     __fadd_rn(__fadd_rn(s[4], s[5]), __fadd_rn(s[6], s[7])));
}

__global__ __launch_bounds__(256) void kP_prep(
        const float* __restrict__ cb, float* __restrict__ bn,
        unsigned short* __restrict__ ebf) {
    const int gid = blockIdx.x * 256 + threadIdx.x;   // 65536 threads
    ebf[gid] = f2bf(cb[gid]);
    if (gid < NE) {
        float row[D];
        const float4* r4 = reinterpret_cast<const float4*>(cb + (size_t)gid * D);
#pragma unroll
        for (int i = 0; i < 16; ++i) {
            float4 v = r4[i];
            row[4*i+0] = v.x; row[4*i+1] = v.y; row[4*i+2] = v.z; row[4*i+3] = v.w;
        }
        bn[gid] = np_sum64_sq(row);
    }
}

// one block = 128 tokens x all 1024 codes. C-init MFMA (-bn/2), max-fold,
// double-buffered staging, non-atomic LDS mask, frozen-exact in-block rerank.
__global__ __launch_bounds__(256, 2) void k_mega(
        const float* __restrict__ in, const unsigned short* __restrict__ ebf,
        const float* __restrict__ bn_g, const float* __restrict__ cb,
        float* __restrict__ out) {
    __shared__ unsigned short ebq[2 * 128 * 64];  // 32 KB double-buffered tile
    __shared__ float sbn[NE];                     // 4 KB  (-0.5*bn)
    __shared__ u64 lmask[128 * MSTRIDE];          // 17 KB (fully overwritten)
    __shared__ unsigned short win_s[128];

    const int tid  = threadIdx.x;
    const int lane = tid & 63, w = tid >> 6;
    const int lcol = lane & 15, lhi = lane >> 4, lrow = lhi * 4;
    const int tokw = blockIdx.x * 128 + w * 32;
    const int b = tokw >> 12, hwb = tokw & 4095;

#pragma unroll
    for (int i = 0; i < 4; ++i)
        sbn[tid + i * 256] = __fmul_rn(-0.5f, bn_g[tid + i * 256]);  // exact *0.5

    // B fragments from input (frozen build, proven R4-R17)
    const float* xbase = in + (size_t)b * (D * HW);
    const int hw0 = hwb + lcol, hw1 = hw0 + 16;
    const int kb = lhi * 8;
    short8 B00, B01, B10, B11;
    {
        const float* p;
        p = xbase + (size_t)kb * HW + hw0;
#pragma unroll
        for (int j = 0; j < 8; ++j) B00[j] = (short)f2bf(p[(size_t)j * HW]);
        p = xbase + (size_t)(kb + 32) * HW + hw0;
#pragma unroll
        for (int j = 0; j < 8; ++j) B01[j] = (short)f2bf(p[(size_t)j * HW]);
        p = xbase + (size_t)kb * HW + hw1;
#pragma unroll
        for (int j = 0; j < 8; ++j) B10[j] = (short)f2bf(p[(size_t)j * HW]);
        p = xbase + (size_t)(kb + 32) * HW + hw1;
#pragma unroll
        for (int j = 0; j < 8; ++j) B11[j] = (short)f2bf(p[(size_t)j * HW]);
    }

    const int swz   = (lcol & 7) << 4;
    const int aoff0 = lcol * 128 + ((lhi * 16) ^ swz);
    const int aoff1 = lcol * 128 + ((64 + lhi * 16) ^ swz);

    int4 pf0, pf1, pf2, pf3;   // prefetch registers
#define LOADC(C) { const int4* s_ = (const int4*)(ebf + (size_t)(C) * 8192);  \
                   pf0 = s_[tid]; pf1 = s_[tid + 256];                        \
                   pf2 = s_[tid + 512]; pf3 = s_[tid + 768]; }
#define WRITEC(BUF) { int4 t_[4] = {pf0, pf1, pf2, pf3};                      \
    _Pragma("unroll")                                                         \
    for (int i = 0; i < 4; ++i) {                                             \
        int L = (tid + i * 256) * 16;                                         \
        int row = L >> 7, wi = L & 127;                                       \
        *(int4*)((char*)ebq + (BUF) * 16384 + row * 128                       \
                 + (wi ^ ((row & 7) << 4))) = t_[i];                          \
    } }

// C-init: acc starts at -bn/2 -> acc = dot - bn/2 ; min t <=> max acc
#define CHUNK_MFMA(BUF, C, CT)                                                \
    const char* lp = (const char*)ebq + (BUF) * 16384 + (CT) * 2048;          \
    short8 A0 = *(const short8*)(lp + aoff0);                                 \
    short8 A1 = *(const short8*)(lp + aoff1);                                 \
    f32x4 cin = *(const f32x4*)(sbn + (C) * 128 + (CT) * 16 + lrow);          \
    f32x4 acc = cin;                                                          \
    acc = __builtin_amdgcn_mfma_f32_16x16x32_bf16(A0, B00, acc, 0, 0, 0);     \
    acc = __builtin_amdgcn_mfma_f32_16x16x32_bf16(A1, B01, acc, 0, 0, 0);     \
    f32x4 ac2 = cin;                                                          \
    ac2 = __builtin_amdgcn_mfma_f32_16x16x32_bf16(A0, B10, ac2, 0, 0, 0);     \
    ac2 = __builtin_amdgcn_mfma_f32_16x16x32_bf16(A1, B11, ac2, 0, 0, 0);

    // ---- pass A: per-token MAX of acc over all chunks (4 indep chains) ----
    f32x4 vA = {-FLT_MAX_F, -FLT_MAX_F, -FLT_MAX_F, -FLT_MAX_F};
    f32x4 vB = vA;
    LOADC(0)
    WRITEC(0)
    __syncthreads();
    for (int c = 0; c < 8; ++c) {
        const int buf = c & 1;
        if (c < 7) LOADC(c + 1)
#pragma unroll
        for (int ct = 0; ct < 8; ++ct) {
            CHUNK_MFMA(buf, c, ct)
#pragma unroll
            for (int r = 0; r < 4; ++r) {
                vA[r] = fmaxf(vA[r], acc[r]);
                vB[r] = fmaxf(vB[r], ac2[r]);
            }
        }
        if (c < 7) WRITEC(buf ^ 1)
        __syncthreads();
    }
    float v0 = fmaxf(fmaxf(vA[0], vA[1]), fmaxf(vA[2], vA[3]));
    float v1 = fmaxf(fmaxf(vB[0], vB[1]), fmaxf(vB[2], vB[3]));
    v0 = fmaxf(v0, __shfl_xor(v0, 16)); v0 = fmaxf(v0, __shfl_xor(v0, 32));
    v1 = fmaxf(v1, __shfl_xor(v1, 16)); v1 = fmaxf(v1, __shfl_xor(v1, 32));
    // acc-space threshold: t <= tmin+M  <=>  acc >= vmax - M/2
    const float athr0 = v0 - 0.5f * MARGIN;
    const float athr1 = v1 - 0.5f * MARGIN;
    const int tA = w * 32 + lcol, tB = tA + 16;       // token-local indices

    // ---- pass B: bit-identical recompute; compare-only mark into registers,
    //      OR-combined across the 4 lhi lanes, stored non-atomically ----
    LOADC(0)
    WRITEC(0)
    __syncthreads();
    for (int c = 0; c < 8; ++c) {
        const int buf = c & 1;
        if (c < 7) LOADC(c + 1)
        u64 w0a = 0, w1a = 0, w0b = 0, w1b = 0;
#pragma unroll
        for (int ct = 0; ct < 8; ++ct) {
            CHUNK_MFMA(buf, c, ct)
#pragma unroll
            for (int r = 0; r < 4; ++r) {
                const int bit = (ct & 3) * 16 + lrow + r;   // j & 63
                if (acc[r] >= athr0) { if (ct < 4) w0a |= 1ull << bit; else w1a |= 1ull << bit; }
                if (ac2[r] >= athr1) { if (ct < 4) w0b |= 1ull << bit; else w1b |= 1ull << bit; }
            }
        }
        w0a |= __shfl_xor(w0a, 16); w0a |= __shfl_xor(w0a, 32);
        w1a |= __shfl_xor(w1a, 16); w1a |= __shfl_xor(w1a, 32);
        w0b |= __shfl_xor(w0b, 16); w0b |= __shfl_xor(w0b, 32);
        w1b |= __shfl_xor(w1b, 16); w1b |= __shfl_xor(w1b, 32);
        if (lhi == 0) {
            lmask[tA * MSTRIDE + 2 * c]     = w0a;
            lmask[tA * MSTRIDE + 2 * c + 1] = w1a;
            lmask[tB * MSTRIDE + 2 * c]     = w0b;
            lmask[tB * MSTRIDE + 2 * c + 1] = w1b;
        }
        if (c < 7) WRITEC(buf ^ 1)
        __syncthreads();
    }

    // ---- rerank: 2 threads/token, frozen-exact, order-independent key min ----
    {
        const int tok_l = tid >> 1, sub = tid & 1;
        const int tok = blockIdx.x * 128 + tok_l;
        const int tb = tok >> 12, thw = tok & 4095;
        const float* x = in + (size_t)tb * (D * HW) + thw;
        float xv[D];
#pragma unroll
        for (int d = 0; d < D; ++d) xv[d] = x[(size_t)d * HW];
        const float a = np_sum64_sq(xv);                      // frozen

        u64 best = ~0ull;
        int kp = -1;
        int pos = 0;
        for (int wd = 0; wd < 16; ++wd) {
            u64 m = lmask[tok_l * MSTRIDE + wd];
            while (m) {
                const int k = wd * 64 + (int)__builtin_ctzll(m);
                m &= m - 1;
                if (((pos++) & 1) != sub) continue;
                if (kp < 0) { kp = k; continue; }
                const float* e0 = cb + (size_t)kp * D;
                const float* e1 = cb + (size_t)k * D;
                float d0 = 0.f, d1 = 0.f;
#pragma unroll
                for (int d = 0; d < 64; ++d) {
                    d0 = __fmaf_rn(xv[d], e0[d], d0);
                    d1 = __fmaf_rn(xv[d], e1[d], d1);
                }
                float q0 = __fsub_rn(__fadd_rn(a, bn_g[kp]), __fmul_rn(2.0f, d0));
                float q1 = __fsub_rn(__fadd_rn(a, bn_g[k]),  __fmul_rn(2.0f, d1));
                u64 key0 = (((u64)__float_as_uint(q0)) << 32) | (unsigned)kp;
                u64 key1 = (((u64)__float_as_uint(q1)) << 32) | (unsigned)k;
                u64 kmin = key0 < key1 ? key0 : key1;
                best = best < kmin ? best : kmin;
                kp = -1;
            }
        }
        if (kp >= 0) {
            const float* e0 = cb + (size_t)kp * D;
            float d0 = 0.f;
#pragma unroll
            for (int d = 0; d < 64; ++d) d0 = __fmaf_rn(xv[d], e0[d], d0);
            float q0 = __fsub_rn(__fadd_rn(a, bn_g[kp]), __fmul_rn(2.0f, d0));
            u64 key0 = (((u64)__float_as_uint(q0)) << 32) | (unsigned)kp;
            best = best < key0 ? best : key0;
        }
        {
            u64 v = __shfl_xor(best, 1);      // tid and tid^1 are same wave
            best = best < v ? best : v;
        }
        if (sub == 0) win_s[tok_l] = (unsigned short)(best & 0x3FFull);
    }
    __syncthreads();

    // ---- gather: 2 threads/token write the winning codebook row ----
    {
        const int tok_l = tid >> 1, half = tid & 1;
        const int tok = blockIdx.x * 128 + tok_l;
        const int gb = tok >> 12, ghw = tok & 4095;
        const unsigned k = win_s[tok_l];
        const float4* er = reinterpret_cast<const float4*>(cb + (size_t)k * D + half * 32);
        float* ot = out + (size_t)gb * (D * HW) + ghw;
#pragma unroll
        for (int i = 0; i < 8; ++i) {
            float4 e = er[i];
            ot[(size_t)(half * 32 + 4*i + 0) * HW] = e.x;
            ot[(size_t)(half * 32 + 4*i + 1) * HW] = e.y;
            ot[(size_t)(half * 32 + 4*i + 2) * HW] = e.z;
            ot[(size_t)(half * 32 + 4*i + 3) * HW] = e.w;
        }
    }
}

extern "C" void kernel_launch(void* const* d_in, const int* in_sizes, int n_in,
                              void* d_out, int out_size, void* d_ws, size_t ws_size,
                              hipStream_t stream) {
    const float* in  = (const float*)d_in[0];
    const float* cb  = (const float*)d_in[1];
    float*       out = (float*)d_out;
    char*        ws  = (char*)d_ws;

    float*          bn  = (float*)(ws + WS_BN);
    unsigned short* ebf = (unsigned short*)(ws + WS_EBF);

    hipLaunchKernelGGL(kP_prep, dim3(256), dim3(256), 0, stream, cb, bn, ebf);
    hipLaunchKernelGGL(k_mega,  dim3(512), dim3(256), 0, stream, in, ebf, bn, cb, out);
}